// Round 17
// baseline (158.773 us; speedup 1.0000x reference)
//
#include <hip/hip_runtime.h>
#include <stdint.h>

#define NROWS 8192
#define DDIM  256
#define K2    512          // hi|lo shorts per row (size bookkeeping only)
#define BLKSTRIDE 131072   // shorts per 256-row block (16 units x 8192)
#define MARGIN_F 0.2f
#define MFMA16 __builtin_amdgcn_mfma_f32_16x16x32_bf16
#define SBAR0() __builtin_amdgcn_sched_barrier(0)

typedef short  short8  __attribute__((ext_vector_type(8)));
typedef float  floatx4 __attribute__((ext_vector_type(4)));

// Unit-packed operand layout (R18, verified absmax 0): each 16KB staging unit
// (blk, kc, hl) is contiguous; slot swizzle baked in at pack time.
__device__ unsigned short gA[(size_t)NROWS * K2];   // im, unit-packed
__device__ unsigned short gB[(size_t)NROWS * K2];   // s,  unit-packed
__device__ float    g_diag[NROWS];
// R26: per-block (bi,bj) stats partials, written with plain coalesced stores
// (replaces 1M scattered device atomics). uint2 = {__float_as_uint(max), cnt}.
__device__ uint2    g_rpart[(size_t)32 * NROWS];    // [bj][bi*256+lrow]  2MB
__device__ uint2    g_cpart[(size_t)32 * NROWS];    // [bi][bj*256+lcol]  2MB
__device__ double   g_outd;
__device__ unsigned g_fin;

__device__ __forceinline__ unsigned short f2bf_rne(float x){
    unsigned u = __float_as_uint(x);
    return (unsigned short)((u + 0x7FFFu + ((u >> 16) & 1u)) >> 16);
}
__device__ __forceinline__ float bf2f(unsigned short h){
    return __uint_as_float(((unsigned)h) << 16);
}
__device__ __forceinline__ unsigned bytesum(unsigned w){
    return (w & 0xFFu) + ((w >> 8) & 0xFFu) + ((w >> 16) & 0xFFu) + (w >> 24);
}

__device__ __forceinline__ void load_lds16(const unsigned short* gptr, void* lptr){
    __builtin_amdgcn_global_load_lds(
        (const __attribute__((address_space(1))) unsigned int*)(uintptr_t)gptr,
        (__attribute__((address_space(3))) unsigned int*)(unsigned)(uintptr_t)lptr,
        16, 0, 0);
}

// One wave per row: fp32 diag dot, hi/lo bf16 split, unit-packed store (R18).
// UNTOUCHED math since R18 (diag summation order feeds the absmax-0 chain);
// R26 only drops the stats zeroing (partials are fully overwritten) and
// resets the finalize accumulator/ticket.
__global__ __launch_bounds__(256) void prep_kernel(const float* __restrict__ im,
                                                   const float* __restrict__ s){
    if (blockIdx.x == 0 && threadIdx.x == 0){ g_outd = 0.0; g_fin = 0u; }

    const int w    = threadIdx.x >> 6;
    const int lane = threadIdx.x & 63;
    const int row  = blockIdx.x * 4 + w;

    const float4 a = ((const float4*)(im + (size_t)row * DDIM))[lane];
    const float4 b = ((const float4*)(s  + (size_t)row * DDIM))[lane];

    float dp = a.x*b.x + a.y*b.y + a.z*b.z + a.w*b.w;
    #pragma unroll
    for (int m = 1; m < 64; m <<= 1) dp += __shfl_xor(dp, m, 64);
    if (lane == 0) g_diag[row] = dp;

    float av[4] = {a.x, a.y, a.z, a.w};
    float bv[4] = {b.x, b.y, b.z, b.w};
    unsigned short ah[4], al[4], bh[4], bl[4];
    #pragma unroll
    for (int i = 0; i < 4; ++i){
        ah[i] = f2bf_rne(av[i]); al[i] = f2bf_rne(av[i] - bf2f(ah[i]));
        bh[i] = f2bf_rne(bv[i]); bl[i] = f2bf_rne(bv[i] - bf2f(bh[i]));
    }
    const int blk = row >> 8, r = row & 255;
    const int kc  = lane >> 3;
    const int sp  = (((lane & 7) >> 1) ^ ((r >> 1) & 3));
    const int hf  = (lane & 1) * 4;
    const size_t ub = (size_t)blk * BLKSTRIDE + (size_t)(kc * 2) * 8192
                    + (size_t)r * 32 + sp * 8 + hf;      // hl=0 unit
    *(ushort4*)&gA[ub       ] = make_ushort4(ah[0], ah[1], ah[2], ah[3]);
    *(ushort4*)&gA[ub + 8192] = make_ushort4(al[0], al[1], al[2], al[3]);  // hl=1
    *(ushort4*)&gB[ub       ] = make_ushort4(bh[0], bh[1], bh[2], bh[3]);
    *(ushort4*)&gB[ub + 8192] = make_ushort4(bl[0], bl[1], bl[2], bl[3]);
}

// Stage one 16KB unit — pure sequential burst. 1024 threads: 1 DMA op each.
__device__ __forceinline__ void stage_unit256(const unsigned short* __restrict__ Obase,
                                              int c, int hl, unsigned short* sb, int tid){
    const unsigned short* u = Obase + (size_t)(c * 2 + hl) * 8192;
    load_lds16(u + (size_t)tid * 8, (char*)sb + tid * 16);
}

// ---- compute helpers (per-element math/order identical since R15) ----
#define MFQ4(A4, B4) { \
    _Pragma("unroll") \
    for (int i_ = 0; i_ < 4; ++i_){ \
        _Pragma("unroll") \
        for (int nj_ = 0; nj_ < 4; ++nj_) \
            acc[i_][nj_] = MFMA16((A4)[i_], (B4)[nj_], acc[i_][nj_], 0, 0, 0); \
    } }
#define LD4(U_, F_, OFF_) { \
    _Pragma("unroll") \
    for (int i_ = 0; i_ < 4; ++i_) \
        (F_)[i_] = *(const short8*)((const char*)(U_) + (OFF_) + i_ * 1024); }

// 256x256 tile, 16 waves (4Mx4N, 64x64/wave), 16x16x32 bf16, 3-pass hi/lo.
// R26 vs R25: K-loop + epilogue phases 1-2 BYTE-IDENTICAL (R25 verified:
// 98us gemm, 46.5% MfmaUtil, 157.2 total). Only the epilogue TAIL changes:
// the 1024 scattered device atomics/block (512 atomicAdd + 512 atomicMax
// with fkey encode — RMW round-trips the convoy can't hide) become plain
// COALESCED partial stores: block (bi,bj) writes 256 row-partials to
// g_rpart[bj][bi*256+..] and 256 col-partials to g_cpart[bi][bj*256+..]
// (2KB contiguous each). Finalize folds the 32 partials per row/col in a
// fixed order (max/int-sum => result identical to the atomic version).
__global__ __launch_bounds__(1024, 1) void gemm_stats_kernel(){
    __shared__ unsigned short U[8][256 * 32];   // loop: staging; epilogue: partials
    __shared__ float drow[256];
    __shared__ float dcol[256];

    const int tid = threadIdx.x;
    const int bid = blockIdx.x;
    // bid[2:0]->XCD band of bi, bid[4:3]->bi within band, bid[9:5]->bj
    const int bi  = (bid & 7) * 4 + ((bid >> 3) & 3);
    const int bj  = bid >> 5;

    if (tid < 256)      drow[tid]       = g_diag[bi * 256 + tid];
    else if (tid < 512) dcol[tid - 256] = g_diag[bj * 256 + (tid - 256)];

    const int w    = tid >> 6, lane = tid & 63;
    const int quad = lane >> 4, l16 = lane & 15;
    const int wr   = w >> 2,   wc  = w & 3;                // 4x4 wave grid
    const int sel  = (quad ^ ((l16 >> 1) & 3)) << 4;       // swizzled 16B slot
    const int aoff = (wr * 64 + l16) * 64 + sel;           // byte off in A units
    const int boff = (wc * 64 + l16) * 64 + sel;           // byte off in B units

    floatx4 acc[4][4] = {};

    const unsigned short* Abase = gA + (size_t)bi * BLKSTRIDE;
    const unsigned short* Bbase = gB + (size_t)bj * BLKSTRIDE;

    // prologue: chunk 0's four units into buffer 0 (4 DMA ops/thread)
    stage_unit256(Abase, 0, 0, U[0], tid);
    stage_unit256(Bbase, 0, 0, U[2], tid);
    stage_unit256(Abase, 0, 1, U[4], tid);
    stage_unit256(Bbase, 0, 1, U[6], tid);
    SBAR0();
    asm volatile("s_waitcnt vmcnt(0)" ::: "memory");
    __builtin_amdgcn_s_barrier();
    SBAR0();

    // K-loop: ONE barrier per chunk (R25, verified).
    #pragma unroll 1
    for (int kc = 0; kc < 8; ++kc){
        const int d = kc & 1, e = d ^ 1;

        if (kc < 7){
            stage_unit256(Abase, kc + 1, 0, U[0 + e], tid);
            stage_unit256(Bbase, kc + 1, 0, U[2 + e], tid);
            stage_unit256(Abase, kc + 1, 1, U[4 + e], tid);
            stage_unit256(Bbase, kc + 1, 1, U[6 + e], tid);
            SBAR0();
        }

        short8 ah[4], bh[4];
        LD4(U[0 + d], ah, aoff); LD4(U[2 + d], bh, boff);
        __builtin_amdgcn_s_setprio(1); MFQ4(ah, bh); __builtin_amdgcn_s_setprio(0);
        {
            short8 al[4]; LD4(U[4 + d], al, aoff);
            __builtin_amdgcn_s_setprio(1); MFQ4(al, bh); __builtin_amdgcn_s_setprio(0);
        }
        {
            short8 bl[4]; LD4(U[6 + d], bl, boff);
            __builtin_amdgcn_s_setprio(1); MFQ4(ah, bl); __builtin_amdgcn_s_setprio(0);
        }

        if (kc < 7){
            asm volatile("s_waitcnt vmcnt(0)" ::: "memory");   // S(kc+1) done (full-chunk cover)
            __builtin_amdgcn_s_barrier();                      // publish e + license d overwrite
            SBAR0();
        }
    }

    // ================= stats epilogue (R19 scheme, 4x4 wave grid) =========
    __syncthreads();                 // all waves done reading U
    char* Lb = (char*)U;
    // layout in U (131072B): RMX f32[256][68] @0       (69,632B, 272B rows)
    //                        RCN u8 [256][72] @69,632  (18,432B)
    //                        CMX f32[256][20] @88,064  (20,480B, 80B rows)
    //                        CCN u8 [256][20] @108,544 (5,120B) -> end 113,664
    float*   RMX = (float*)Lb;
    uint8_t* RCN = (uint8_t*)(Lb + 69632);
    float*   CMX = (float*)(Lb + 88064);
    uint8_t* CCN = (uint8_t*)(Lb + 108544);

    const int c = wc * 16 + l16;     // row-partial slot [0,64)
    const int q = wr * 4 + quad;     // col-partial slot [0,16)

    // rows: fold 4 lane-local cols per (mi,r)  (16 rows/thread)
    #pragma unroll
    for (int mi = 0; mi < 4; ++mi){
        #pragma unroll
        for (int r = 0; r < 4; ++r){
            const int lrow = wr * 64 + mi * 16 + quad * 4 + r;
            const int gi   = bi * 256 + lrow;
            const float dv = drow[lrow];
            int cnt = 0; float mx = -3.0e38f;
            #pragma unroll
            for (int nj = 0; nj < 4; ++nj){
                const int gj  = bj * 256 + wc * 64 + nj * 16 + l16;
                const float v = acc[mi][nj][r];
                if (gi != gj){ cnt += (v < dv) ? 1 : 0; mx = fmaxf(mx, v); }
            }
            RMX[lrow * 68 + c] = mx;
            RCN[lrow * 72 + c] = (uint8_t)cnt;
        }
    }
    // cols: fold 16 lane-local rows per nj (4 cols/thread)
    #pragma unroll
    for (int nj = 0; nj < 4; ++nj){
        const int lcol = wc * 64 + nj * 16 + l16;
        const int gj   = bj * 256 + lcol;
        const float dv = dcol[lcol];
        int cnt = 0; float mx = -3.0e38f;
        #pragma unroll
        for (int mi = 0; mi < 4; ++mi){
            #pragma unroll
            for (int r = 0; r < 4; ++r){
                const int gi  = bi * 256 + wr * 64 + mi * 16 + quad * 4 + r;
                const float v = acc[mi][nj][r];
                if (gi != gj){ cnt += (v < dv) ? 1 : 0; mx = fmaxf(mx, v); }
            }
        }
        CMX[lcol * 20 + q] = mx;
        CCN[lcol * 20 + q] = (uint8_t)cnt;
    }
    __syncthreads();

    // ---- tail: block-level reduce -> ONE coalesced partial store/thread ----
    if (tid < 256){
        const int lrow = tid;
        const float4* rp = (const float4*)(Lb + (size_t)lrow * 272);
        float mx = -3.0e38f;
        #pragma unroll
        for (int k = 0; k < 16; ++k){
            const float4 v = rp[k];
            mx = fmaxf(mx, fmaxf(fmaxf(v.x, v.y), fmaxf(v.z, v.w)));
        }
        const uint2* cp = (const uint2*)(Lb + 69632 + (size_t)lrow * 72);
        unsigned cs = 0;
        #pragma unroll
        for (int k = 0; k < 8; ++k){
            const uint2 wv = cp[k];
            cs += bytesum(wv.x) + bytesum(wv.y);
        }
        g_rpart[(size_t)bj * NROWS + bi * 256 + lrow] = make_uint2(__float_as_uint(mx), cs);
    } else if (tid < 512){
        const int lcol = tid - 256;
        const float4* qp = (const float4*)(Lb + 88064 + (size_t)lcol * 80);
        float mx = -3.0e38f;
        #pragma unroll
        for (int k = 0; k < 4; ++k){
            const float4 v = qp[k];
            mx = fmaxf(mx, fmaxf(fmaxf(v.x, v.y), fmaxf(v.z, v.w)));
        }
        const unsigned* cq = (const unsigned*)(Lb + 108544 + (size_t)lcol * 20);
        unsigned cs = 0;
        #pragma unroll
        for (int k = 0; k < 4; ++k) cs += bytesum(cq[k]);
        g_cpart[(size_t)bi * NROWS + bj * 256 + lcol] = make_uint2(__float_as_uint(mx), cs);
    }
}

// 16 blocks x 1024 threads: thread owns one row (g<8192) or col. Folds its
// 32 partials in fixed order (max/int-sum — identical result to the old
// atomic path), computes the hinge term, block double-tree, double
// atomicAdd into g_outd; last-of-16 ticket writes out. The agent-scope
// fence here is safe: 16 fences in a trailing microkernel with nothing
// co-resident (R22's failure was 1024 fences DURING the hot dispatch).
__global__ __launch_bounds__(1024) void finalize_kernel(float* __restrict__ out){
    __shared__ double red[1024];
    const int g = blockIdx.x * 1024 + threadIdx.x;   // [0, 16384)
    const int isRow = (g < NROWS);
    const int i     = isRow ? g : (g - NROWS);
    const uint2* part = isRow ? g_rpart : g_cpart;

    const float d = g_diag[i];
    float mx = -3.0e38f; unsigned cs = 0;
    #pragma unroll 4
    for (int p = 0; p < 32; ++p){
        const uint2 v = part[(size_t)p * NROWS + i];
        mx = fmaxf(mx, __uint_as_float(v.x));
        cs += v.y;
    }
    red[threadIdx.x] = (double)(fmaxf(MARGIN_F + mx - d, 0.0f) * (1.0f / (float)(cs + 1u)));
    __syncthreads();
    for (int s2 = 512; s2 > 0; s2 >>= 1){
        if (threadIdx.x < s2) red[threadIdx.x] += red[threadIdx.x + s2];
        __syncthreads();
    }
    if (threadIdx.x == 0){
        atomicAdd(&g_outd, red[0]);
        __threadfence();
        const unsigned prev = __hip_atomic_fetch_add(&g_fin, 1u,
                                 __ATOMIC_ACQ_REL, __HIP_MEMORY_SCOPE_AGENT);
        if (prev == 15u){
            const double v = __hip_atomic_load(&g_outd, __ATOMIC_RELAXED,
                                               __HIP_MEMORY_SCOPE_AGENT);
            out[0] = (float)v;
        }
    }
}

extern "C" void kernel_launch(void* const* d_in, const int* in_sizes, int n_in,
                              void* d_out, int out_size, void* d_ws, size_t ws_size,
                              hipStream_t stream){
    const float* im = (const float*)d_in[0];
    const float* s  = (const float*)d_in[1];
    float* out = (float*)d_out;

    prep_kernel<<<NROWS / 4, 256, 0, stream>>>(im, s);
    gemm_stats_kernel<<<1024, 1024, 0, stream>>>();
    finalize_kernel<<<16, 1024, 0, stream>>>(out);
}